// Round 11
// baseline (745.921 us; speedup 1.0000x reference)
//
#include <hip/hip_runtime.h>
#include <hip/hip_bf16.h>

#define D_    768
#define P_    1536
#define HID_  768
#define NH_   8
#define DH_   96
#define S_    2048
#define LCH   256     // recurrence chunk length
#define NCH   8       // chunks per sequence

typedef __hip_bfloat16 bf16_t;
typedef __attribute__((ext_vector_type(8))) short s16x8;
typedef __attribute__((ext_vector_type(8))) unsigned short u16x8;
typedef __attribute__((ext_vector_type(4))) float f32x4;

__device__ __forceinline__ float b2f(unsigned short u) {
    union { unsigned int i; float f; } x; x.i = ((unsigned int)u) << 16; return x.f;
}
__device__ __forceinline__ unsigned short f2b(float f) {
    bf16_t h = __float2bfloat16(f);
    unsigned short u; __builtin_memcpy(&u, &h, 2); return u;
}
__device__ __forceinline__ bf16_t u2b(unsigned short u) {
    bf16_t t; __builtin_memcpy(&t, &u, 2); return t;
}

// async global->LDS, 16B per lane (LDS dest = wave-uniform base + lane*16, linear layout)
__device__ __forceinline__ void gload16(const void* g, const void* l) {
    __builtin_amdgcn_global_load_lds(
        (const __attribute__((address_space(1))) unsigned int*)(unsigned long long)(g),
        (__attribute__((address_space(3))) unsigned int*)(unsigned int)(unsigned long long)(l),
        16, 0, 0);
}
// non-temporal variant (aux=2 -> SLC/NT): streaming data, evict-first in L2.
// Used for A-panel staging so the activation stream doesn't flush the L2-resident W panels.
__device__ __forceinline__ void gload16nt(const void* g, const void* l) {
    __builtin_amdgcn_global_load_lds(
        (const __attribute__((address_space(1))) unsigned int*)(unsigned long long)(g),
        (__attribute__((address_space(3))) unsigned int*)(unsigned int)(unsigned long long)(l),
        16, 0, 2);
}

// ---------------- all weight conversions in one grid-stride kernel ----------------
__global__ void cvt_all_kernel(const float* __restrict__ up_l_w, const float* __restrict__ up_r_w,
                               const float* __restrict__ skip_w, const float* __restrict__ fused_w,
                               const float* __restrict__ down_w,
                               bf16_t* __restrict__ win_h, bf16_t* __restrict__ win_l,
                               bf16_t* __restrict__ wcat, bf16_t* __restrict__ wdn) {
    const int N1 = 2304 * 768, N2 = 3840 * 1536, N3 = 768 * 768;
    int i = blockIdx.x * blockDim.x + threadIdx.x;
    const int stride = gridDim.x * blockDim.x;
    for (; i < N1 + N2 + N3; i += stride) {
        if (i < N1) {
            const float x = (i < 1536 * 768) ? up_l_w[i] : up_r_w[i - 1536 * 768];
            const bf16_t h = __float2bfloat16(x);
            win_h[i] = h;
            win_l[i] = __float2bfloat16(x - __bfloat162float(h));
        } else if (i < N1 + N2) {
            const int j = i - N1;
            const float x = (j < 768 * 1536) ? skip_w[j] : fused_w[16 * 1536 + (j - 768 * 1536)];
            wcat[j] = __float2bfloat16(x);
        } else {
            wdn[i - N1 - N2] = __float2bfloat16(down_w[i - N1 - N2]);
        }
    }
}

// ---------------- LayerNorm(x) -> compact bf16 [T,768] ----------------
__global__ __launch_bounds__(256) void ln_x_kernel(const float* __restrict__ x,
                                                   const float* __restrict__ w,
                                                   const float* __restrict__ b,
                                                   bf16_t* __restrict__ xn) {
    const int t = blockIdx.x, tid = threadIdx.x;
    const size_t rb = (size_t)t * D_;
    float v0 = x[rb + tid], v1 = x[rb + tid + 256], v2 = x[rb + tid + 512];
    float sm = v0 + v1 + v2;
    float sq = v0 * v0 + v1 * v1 + v2 * v2;
#pragma unroll
    for (int off = 32; off > 0; off >>= 1) { sm += __shfl_xor(sm, off); sq += __shfl_xor(sq, off); }
    __shared__ float ws4[8];
    const int wid = tid >> 6, lane = tid & 63;
    if (lane == 0) { ws4[wid] = sm; ws4[4 + wid] = sq; }
    __syncthreads();
    sm = ws4[0] + ws4[1] + ws4[2] + ws4[3];
    sq = ws4[4] + ws4[5] + ws4[6] + ws4[7];
    const float mu = sm * (1.f / D_);
    const float rs = rsqrtf(sq * (1.f / D_) - mu * mu + 1e-6f);
    bf16_t* row = xn + rb;
#pragma unroll
    for (int k2 = 0; k2 < 3; ++k2) {
        const int c = tid + k2 * 256;
        const float v = (k2 == 0 ? v0 : k2 == 1 ? v1 : v2);
        row[c] = __float2bfloat16((v - mu) * rs * w[c] + b[c]);
    }
}

// ---------------- conv(K=4)+SiLU from fp32 xl; writes compact xc-hi plane; fp32 gates fused ----------------
__global__ __launch_bounds__(192) void conv_gate_kernel(const float* __restrict__ xl,
                                                        const float* __restrict__ cw,
                                                        const float* __restrict__ fw,
                                                        const float* __restrict__ fb,
                                                        bf16_t* __restrict__ xch,
                                                        float* __restrict__ gates) {
    const int t = blockIdx.x, c = threadIdx.x;   // c: 8-float chunk, 192*8 = 1536
    const float* row = xl + (size_t)t * P_;
    const float4* r4 = (const float4*)row;
    float4 a = r4[2 * c], b4 = r4[2 * c + 1];
    float pm3 = 0.f, pm2 = 0.f, pm1 = 0.f;
    if (c > 0) { pm3 = row[c * 8 - 3]; pm2 = row[c * 8 - 2]; pm1 = row[c * 8 - 1]; }
    const float w0 = cw[0], w1 = cw[1], w2 = cw[2], w3 = cw[3];
    float xv[11] = {pm3, pm2, pm1, a.x, a.y, a.z, a.w, b4.x, b4.y, b4.z, b4.w};
    float xc[8];
    u16x8 h8;
#pragma unroll
    for (int j = 0; j < 8; ++j) {
        float s = w0 * xv[j] + w1 * xv[j + 1] + w2 * xv[j + 2] + w3 * xv[j + 3];
        s = s * (1.f / (1.f + __expf(-s)));   // SiLU
        xc[j] = s;
        h8[j] = f2b(s);
    }
    *(u16x8*)(xch + (size_t)t * P_ + c * 8) = h8;

    // fused exact-fp32 gate dots
    float pj[16];
#pragma unroll
    for (int j = 0; j < 16; ++j) {
        const float* wr = fw + (size_t)j * P_ + c * 8;
        float p = 0.f;
#pragma unroll
        for (int u = 0; u < 8; ++u) p += xc[u] * wr[u];
        pj[j] = p;
    }
#pragma unroll
    for (int j = 0; j < 16; ++j)
#pragma unroll
        for (int off = 32; off > 0; off >>= 1) pj[j] += __shfl_xor(pj[j], off);
    __shared__ float red[3][16];
    const int wv = c >> 6, ln = c & 63;
    if (ln == 0) {
#pragma unroll
        for (int j = 0; j < 16; ++j) red[wv][j] = pj[j];
    }
    __syncthreads();
    if (c < 16) {
        const float z = red[0][c] + red[1][c] + red[2][c] + fb[c];
        gates[(size_t)t * 16 + c] = 15.f * tanhf(z * (1.f / 15.f));
    }
}

// ============== 256x256 8-phase pipelined bf16 MFMA GEMM, C = A[M,K] * W[N,K]^T ==============
// Same schedule as round 10 (passed, race-free), plus: A-panel staging uses NON-TEMPORAL
// loads (gload16nt) so the streaming activation panels don't evict the W panels from L2.
// With GN=3 nt-grouping, each XCD's 3 W panels (2.3 MB) should now stay L2-resident across
// all 64 mt steps; only the A stream rides the L2-miss fabric path (~half the staged bytes).
template <int NPASS, int MODE, int KTP>
__global__ __launch_bounds__(512, 2) void gemm256(
    const char* __restrict__ Ab, int astride, int aloff,
    const bf16_t* __restrict__ Wh, const bf16_t* __restrict__ Wl,
    bf16_t* __restrict__ out0, float* __restrict__ outf, int ldout,
    bf16_t* __restrict__ p1, bf16_t* __restrict__ p2,
    bf16_t* __restrict__ p3, bf16_t* __restrict__ p4,
    const float* __restrict__ bias, const float* __restrict__ resid) {
    __shared__ char smem[131072];
    const int tid = threadIdx.x;
    const int gx = gridDim.x, gy = gridDim.y;
    const int orig = blockIdx.y * gx + blockIdx.x;
    const int cpx = (gx * gy) >> 3;
    const int logical = (orig & 7) * cpx + (orig >> 3);   // XCD-contiguous
    constexpr int GN = 3;                                  // nt-group width (gx % 3 == 0)
    const int bpg = GN * gy;
    const int grp = logical / bpg, rem = logical - grp * bpg;
    const int mt = rem / GN;
    const int nt = grp * GN + (rem - mt * GN);
    const int wid = tid >> 6, lane = tid & 63;
    const int wm = wid >> 2, wn = wid & 3;
    const int l15 = lane & 15, l4 = lane >> 4;
    const int sw = l15 & 7;
    const int co0 = ((l4 ^ sw) << 4);
    const int co1 = (((4 | l4) ^ sw) << 4);
    const int brb = (wn & 1) * 64;
    constexpr int VT = NPASS * KTP;
    const int vtm = (MODE == 4 && nt >= 6) ? KTP : VT;   // MODE 4 r-cols: Wh pass only
    const size_t wstride = (size_t)KTP * 128;   // W row bytes

    auto stage = [&](int h) {
        const int t = h >> 2;
        if (t >= vtm) return;
        const int m = h & 3;
        const int pass = t / KTP;
        const int k0b = (t - pass * KTP) << 7;
        char* ldsdst = smem + (size_t)(h & 7) * 16384;
        const int r0 = tid >> 3, cd = tid & 7;
        if (m < 2) {
            const char* src = Ab + (pass == 2 ? aloff : 0) + (size_t)(mt * 256 + m * 128) * astride + k0b;
#pragma unroll
            for (int l = 0; l < 2; ++l) {
                const int row = l * 64 + r0;
                gload16nt(src + (size_t)row * (size_t)astride + (size_t)((cd ^ (row & 7)) << 4),
                          ldsdst + l * 8192 + tid * 16);
            }
        } else {
            const bf16_t* wp = (pass == 1) ? Wl : Wh;
            const char* src = (const char*)wp + (size_t)(nt * 256 + (m - 2) * 128) * wstride + k0b;
#pragma unroll
            for (int l = 0; l < 2; ++l) {
                const int row = l * 64 + r0;
                gload16(src + (size_t)row * wstride + (size_t)((cd ^ (row & 7)) << 4),
                        ldsdst + l * 8192 + tid * 16);
            }
        }
    };

    s16x8 a03[4], a03b[4], a47[4], a47b[4], b01[2], b01b[2], b23[2], b23b[2];
    auto readA03 = [&](const char* ldsA) {
#pragma unroll
        for (int i = 0; i < 4; ++i) {
            const char* rp = ldsA + (i * 16 + l15) * 128;
            a03[i] = *(const s16x8*)(rp + co0);
            a03b[i] = *(const s16x8*)(rp + co1);
        }
    };
    auto readA47 = [&](const char* ldsA) {
#pragma unroll
        for (int i = 0; i < 4; ++i) {
            const char* rp = ldsA + ((4 + i) * 16 + l15) * 128;
            a47[i] = *(const s16x8*)(rp + co0);
            a47b[i] = *(const s16x8*)(rp + co1);
        }
    };
    auto readB01 = [&](const char* ldsB) {
#pragma unroll
        for (int j = 0; j < 2; ++j) {
            const char* rp = ldsB + (brb + j * 16 + l15) * 128;
            b01[j] = *(const s16x8*)(rp + co0);
            b01b[j] = *(const s16x8*)(rp + co1);
        }
    };
    auto readB23 = [&](const char* ldsB) {
#pragma unroll
        for (int j = 0; j < 2; ++j) {
            const char* rp = ldsB + (brb + 32 + j * 16 + l15) * 128;
            b23[j] = *(const s16x8*)(rp + co0);
            b23b[j] = *(const s16x8*)(rp + co1);
        }
    };

    f32x4 acc[8][4];
#pragma unroll
    for (int i = 0; i < 8; ++i)
#pragma unroll
        for (int j = 0; j < 4; ++j) acc[i][j] = f32x4{0.f, 0.f, 0.f, 0.f};

    // prologue: tile0 all 4 halves + tile1 A-halves; pre-read tile0's ph0 operands
#pragma unroll
    for (int h = 0; h < 6; ++h) stage(h);
    asm volatile("s_waitcnt vmcnt(4)" ::: "memory");
    __builtin_amdgcn_s_barrier();
    readA03(smem + wm * 16384);
    readB01(smem + 32768 + (wn >> 1) * 16384);

    for (int vt = 0; vt < vtm; ++vt) {
        const char* ldsA = smem + (vt & 1) * 65536 + wm * 16384;
        const char* ldsB = smem + (vt & 1) * 65536 + 32768 + (wn >> 1) * 16384;
        const char* ldsAn = smem + ((vt + 1) & 1) * 65536 + wm * 16384;
        const char* ldsBn = smem + ((vt + 1) & 1) * 65536 + 32768 + (wn >> 1) * 16384;
        const int hb = vt * 4 + 6;

        // ---- phase 0: MFMA a03 x b01; prefetch b23; stage next tile's BOTH B halves
        stage(hb + 0);
        stage(hb + 1);
        __builtin_amdgcn_s_barrier();
        readB23(ldsB);
        __builtin_amdgcn_s_setprio(1);
#pragma unroll
        for (int i = 0; i < 4; ++i)
#pragma unroll
            for (int j = 0; j < 2; ++j) {
                acc[i][j] = __builtin_amdgcn_mfma_f32_16x16x32_bf16(a03[i], b01[j], acc[i][j], 0, 0, 0);
                acc[i][j] = __builtin_amdgcn_mfma_f32_16x16x32_bf16(a03b[i], b01b[j], acc[i][j], 0, 0, 0);
            }
        __builtin_amdgcn_s_setprio(0);
        asm volatile("s_waitcnt lgkmcnt(0)" ::: "memory");
        __builtin_amdgcn_s_barrier();

        // ---- phase 1: MFMA a03 x b23; prefetch a47 (no stage)
        __builtin_amdgcn_s_barrier();
        readA47(ldsA);
        __builtin_amdgcn_s_setprio(1);
#pragma unroll
        for (int i = 0; i < 4; ++i)
#pragma unroll
            for (int j = 0; j < 2; ++j) {
                acc[i][2 + j] = __builtin_amdgcn_mfma_f32_16x16x32_bf16(a03[i], b23[j], acc[i][2 + j], 0, 0, 0);
                acc[i][2 + j] = __builtin_amdgcn_mfma_f32_16x16x32_bf16(a03b[i], b23b[j], acc[i][2 + j], 0, 0, 0);
            }
        __builtin_amdgcn_s_setprio(0);
        asm volatile("s_waitcnt lgkmcnt(0)" ::: "memory");
        __builtin_amdgcn_s_barrier();

        // ---- phase 2: MFMA a47 x b01; stage tile(t+2) A0; drain next tile's 4 halves
        stage(hb + 2);
        __builtin_amdgcn_s_barrier();
        __builtin_amdgcn_s_setprio(1);
#pragma unroll
        for (int i = 0; i < 4; ++i)
#pragma unroll
            for (int j = 0; j < 2; ++j) {
                acc[4 + i][j] = __builtin_amdgcn_mfma_f32_16x16x32_bf16(a47[i], b01[j], acc[4 + i][j], 0, 0, 0);
                acc[4 + i][j] = __builtin_amdgcn_mfma_f32_16x16x32_bf16(a47b[i], b01b[j], acc[4 + i][j], 0, 0, 0);
            }
        __builtin_amdgcn_s_setprio(0);
        if (vt + 2 >= vtm) {   // TAIL: newest stages skipped -> must drain everything
            asm volatile("s_waitcnt vmcnt(0)" ::: "memory");
        } else {
            asm volatile("s_waitcnt vmcnt(2)" ::: "memory");
        }
        __builtin_amdgcn_s_barrier();

        // ---- phase 3: MFMA a47 x b23; stage tile(t+2) A1; prefetch next tile's a03,b01
        stage(hb + 3);
        __builtin_amdgcn_s_barrier();
        if (vt + 1 < vtm) { readA03(ldsAn); readB01(ldsBn); }
        __builtin_amdgcn_s_setprio(1);
#pragma unroll
        for (int i = 0; i < 4; ++i)
#pragma unroll
            for (int j = 0; j < 2; ++j) {
                acc[4 + i][2 + j] = __builtin_amdgcn_mfma_f32_16x16x32_bf16(a47[i], b23[j], acc[4 + i][2 + j], 0, 0, 0);
                acc[4 + i][2 + j] = __builtin_amdgcn_mfma_f32_16x16x32_bf16(a47b[i], b23b[j], acc[4 + i][2 + j], 0, 0, 0);
            }
        __builtin_amdgcn_s_setprio(0);
        asm volatile("s_waitcnt lgkmcnt(0)" ::: "memory");
        __builtin_amdgcn_s_barrier();
    }

    // ---- epilogue ----
    const int grow0 = mt * 256 + wm * 128;
    const int gcol0 = nt * 256 + wn * 64;
#pragma unroll
    for (int i = 0; i < 8; ++i) {
#pragma unroll
        for (int j = 0; j < 4; ++j) {
            const int gcol = gcol0 + j * 16 + l15;
#pragma unroll
            for (int r = 0; r < 4; ++r) {
                const int grow = grow0 + i * 16 + l4 * 4 + r;
                float v = acc[i][j][r];
                if constexpr (MODE == 0) {
                    out0[(size_t)grow * ldout + gcol] = __float2bfloat16(v);
                } else if constexpr (MODE == 1) {
                    outf[(size_t)grow * ldout + gcol] = v;
                } else if constexpr (MODE == 2) {
                    const int seg = gcol / 768;          // uniform per block (768 % 256 == 0)
                    const int col = gcol - seg * 768;
                    const size_t oo = (size_t)grow * 768 + col;
                    if (seg == 0) {
                        out0[oo] = __float2bfloat16(v);  // skip (no bias)
                    } else {
                        v += bias[gcol - 768];
                        if (seg == 1)      p1[oo] = __float2bfloat16(1.f / (1.f + __expf(-v)));
                        else if (seg == 2) p2[oo] = __float2bfloat16(v);
                        else if (seg == 3) p3[oo] = __float2bfloat16(v * 0.10206207261596577f); // 1/sqrt(96)
                        else               p4[oo] = __float2bfloat16(v);
                    }
                } else if constexpr (MODE == 3) {
                    const size_t oo = (size_t)grow * ldout + gcol;
                    outf[oo] = v + resid[oo];
                } else {   // MODE 4: merged up (xl fp32 | r bf16)
                    if (gcol < 1536) outf[(size_t)grow * 1536 + gcol] = v;
                    else             out0[(size_t)grow * 768 + (gcol - 1536)] = __float2bfloat16(v);
                }
            }
        }
    }
}

// ================= chunkwise-parallel mLSTM recurrence =================
// ---- 1. gate scan ----
__global__ __launch_bounds__(64) void mscan_kernel(const float* __restrict__ gates,
                                                   float* __restrict__ wAo, float* __restrict__ go,
                                                   float* __restrict__ mprev, float* __restrict__ alpha) {
    const int b = blockIdx.x;
    const int lane = threadIdx.x;
    const int hd = lane >> 3, c = lane & 7;
    const size_t gbase = ((size_t)b * S_ + c * LCH) * 16;
    float F = 0.f, I = -1e30f;
    for (int t = 0; t < LCH; ++t) {
        const float fi = gates[gbase + t * 16 + hd];
        const float ff = gates[gbase + t * 16 + 8 + hd];
        I = fmaxf(I + ff, fi);
        F += ff;
    }
    float Fs = F, Is = I;
#pragma unroll
    for (int off = 1; off < 8; off <<= 1) {
        const float Fo = __shfl_up(Fs, off);
        const float Io = __shfl_up(Is, off);
        if (c >= off) { Is = fmaxf(Io + Fs, Is); Fs = Fo + Fs; }
    }
    const float Fe = __shfl_up(Fs, 1);
    const float Ie = __shfl_up(Is, 1);
    const float mp = (c == 0) ? 0.f : fmaxf(Fe, Ie);
    float m = mp; F = 0.f;
    const size_t wbase = ((size_t)(b * NH_ + hd)) * S_ + c * LCH;
    for (int t = 0; t < LCH; ++t) {
        const float fi = gates[gbase + t * 16 + hd];
        const float ff = gates[gbase + t * 16 + 8 + hd];
        F += ff;
        m = fmaxf(ff + m, fi);
        wAo[wbase + t] = fi - F;
        go[wbase + t] = F - m;
    }
    const int idx = (b * NH_ + hd) * NCH + c;
    mprev[idx] = mp;
    alpha[idx] = __expf(fminf(mp + F - m, 0.f));
}

// ---- 2. chunk summaries: B_c = sum coeff_s v_s k_s^T; nB rides as vT row 96 = coeff ----
__global__ __launch_bounds__(512) void chunkA_kernel(
    const bf16_t* __restrict__ kb, const bf16_t* __restrict__ vb,
    const float* __restrict__ wAo, const float* __restrict__ go,
    float* __restrict__ Bst) {
    const int c = blockIdx.x, bh = blockIdx.y;
    const int b = bh >> 3, hd = bh & 7;
    __shared__ bf16_t kT[96 * 136];
    __shared__ bf16_t vTh[112 * 136];    // rows 0..95 = coeff*v^T, row 96 = coeff, 97..111 = 0
    __shared__ float coeffL[128];
    const int tid = threadIdx.x, lane = tid & 63, wid = tid >> 6;
    const int l15 = lane & 15, l4 = lane >> 4;
    const int s0 = c * LCH;
    const size_t seqb = (size_t)bh * S_;
    const float gend = go[seqb + s0 + LCH - 1];
    f32x4 acc[6];
#pragma unroll
    for (int nf = 0; nf < 6; ++nf) acc[nf] = f32x4{0.f, 0.f, 0.f, 0.f};

    {
        const bf16_t z16 = __float2bfloat16(0.f);
        for (int i = tid; i < 15 * 136; i += 512) vTh[97 * 136 + i] = z16;
    }

    for (int sb = 0; sb < 2; ++sb) {
        __syncthreads();
        if (tid < 128) {
            const float cf = __expf(fminf(wAo[seqb + s0 + sb * 128 + tid] + gend, 0.f));
            coeffL[tid] = cf;
            vTh[96 * 136 + tid] = __float2bfloat16(cf);
        }
        __syncthreads();
        {
            const int st = tid >> 2, e0 = (tid & 3) * 24;
            const size_t rowb = (size_t)(b * S_ + s0 + sb * 128 + st) * HID_ + hd * DH_ + e0;
            const float cf = coeffL[st];
#pragma unroll
            for (int jj = 0; jj < 3; ++jj) {
                const u16x8 kv = *(const u16x8*)(kb + rowb + jj * 8);
                const u16x8 vv = *(const u16x8*)(vb + rowb + jj * 8);
#pragma unroll
                for (int u = 0; u < 8; ++u) {
                    const int e = e0 + jj * 8 + u;
                    kT[e * 136 + st] = u2b(kv[u]);
                    vTh[e * 136 + st] = __float2bfloat16(b2f(vv[u]) * cf);
                }
            }
        }
        __syncthreads();
        if (wid < 7) {
#pragma unroll
            for (int ks = 0; ks < 4; ++ks) {
                const s16x8 af = *(const s16x8*)((const char*)vTh + (wid * 16 + l15) * 272 + ks * 64 + l4 * 16);
#pragma unroll
                for (int nf = 0; nf < 6; ++nf) {
                    const s16x8 bf = *(const s16x8*)((const char*)kT + (nf * 16 + l15) * 272 + ks * 64 + l4 * 16);
                    acc[nf] = __builtin_amdgcn_mfma_f32_16x16x32_bf16(af, bf, acc[nf], 0, 0, 0);
                }
            }
        }
    }
    float* outp = Bst + ((size_t)bh * NCH + c) * 9312;
    if (wid < 6) {
#pragma unroll
        for (int nf = 0; nf < 6; ++nf)
#pragma unroll
            for (int r = 0; r < 4; ++r)
                outp[(size_t)(wid * 16 + l4 * 4 + r) * 96 + nf * 16 + l15] = acc[nf][r];
    } else if (wid == 6 && l4 == 0) {
#pragma unroll
        for (int nf = 0; nf < 6; ++nf)
            outp[9216 + nf * 16 + l15] = acc[nf][0];
    }
}

// ---- 3. inter-chunk scan, in-place ----
__global__ __launch_bounds__(96) void chunkB_kernel(float* __restrict__ Bst,
                                                    const float* __restrict__ alpha) {
    const int idx = blockIdx.x * 96 + threadIdx.x;
    const int bh = blockIdx.y;
    float val = (idx < 9216) ? 0.f : 1.f;
    for (int c = 0; c < NCH; ++c) {
        float* p = Bst + ((size_t)bh * NCH + c) * 9312 + idx;
        const float t = *p;
        *p = val;
        val = alpha[bh * NCH + c] * val + t;
    }
}

// ---- 4. outputs: h = o * (inter + intra)/max(den,1), 64 q-rows per block ----
__global__ __launch_bounds__(256) void chunkC_kernel(
    const bf16_t* __restrict__ qb, const bf16_t* __restrict__ kb,
    const bf16_t* __restrict__ vb, const bf16_t* __restrict__ ob,
    const float* __restrict__ wAo, const float* __restrict__ go,
    const float* __restrict__ mprev, const float* __restrict__ Cst,
    float* __restrict__ hb) {
    const int c = blockIdx.x >> 2, qblk = blockIdx.x & 3;
    const int bh = blockIdx.y, b = bh >> 3, hd = bh & 7;
    __shared__ bf16_t Qs[64 * 104];
    __shared__ bf16_t Ks[64 * 104];
    __shared__ bf16_t vTs[112 * 72];
    __shared__ bf16_t Phs[64 * 72];
    __shared__ bf16_t CsH[112 * 104];
    __shared__ float wAL[256];
    __shared__ float gL[64];
    __shared__ float scL[64];
    const int tid = threadIdx.x, lane = tid & 63, wid = tid >> 6;
    const int l15 = lane & 15, l4 = lane >> 4;
    const int s0 = c * LCH;
    const size_t seqb = (size_t)bh * S_;
    const int tq0 = b * S_ + s0 + qblk * 64;

    wAL[tid] = wAo[seqb + s0 + tid];
    if (tid < 64) {
        const float gg = go[seqb + s0 + qblk * 64 + tid];
        gL[tid] = gg;
        scL[tid] = __expf(fminf(mprev[bh * NCH + c] + gg, 0.f));
    }
    {
        const int tt = tid >> 2, e0 = (tid & 3) * 24;
        const bf16_t* qrow = qb + (size_t)(tq0 + tt) * HID_ + hd * DH_ + e0;
#pragma unroll
        for (int jj = 0; jj < 3; ++jj)
            *(u16x8*)&Qs[tt * 104 + e0 + jj * 8] = *(const u16x8*)(qrow + jj * 8);
    }
    {
        const float* Csp = Cst + ((size_t)bh * NCH + c) * 9312;
        for (int i = tid; i < 9312; i += 256) {
            int dd, ee;
            if (i < 9216) { dd = i / 96; ee = i - dd * 96; }
            else          { dd = 96;     ee = i - 9216; }
            CsH[dd * 104 + ee] = __float2bfloat16(Csp[i]);
        }
        const bf16_t z16 = __float2bfloat16(0.f);
        for (int i = tid; i < 15 * 104; i += 256) CsH[97 * 104 + i] = z16;
        if (tid < 64) vTs[96 * 72 + tid] = __float2bfloat16(1.f);
        for (int i = tid; i < 15 * 72; i += 256) vTs[97 * 72 + i] = z16;
    }
    __syncthreads();

    f32x4 acc[7];
#pragma unroll
    for (int nf = 0; nf < 7; ++nf) acc[nf] = f32x4{0.f, 0.f, 0.f, 0.f};
#pragma unroll
    for (int ks = 0; ks < 3; ++ks) {
        const s16x8 af = *(const s16x8*)((const char*)Qs + (wid * 16 + l15) * 208 + ks * 64 + l4 * 16);
#pragma unroll
        for (int nf = 0; nf < 7; ++nf) {
            const s16x8 bf = *(const s16x8*)((const char*)CsH + (nf * 16 + l15) * 208 + ks * 64 + l4 * 16);
            acc[nf] = __builtin_amdgcn_mfma_f32_16x16x32_bf16(af, bf, acc[nf], 0, 0, 0);
        }
    }
    {
        float scr[4];
#pragma unroll
        for (int r = 0; r < 4; ++r) scr[r] = scL[wid * 16 + l4 * 4 + r];
#pragma unroll
        for (int nf = 0; nf < 7; ++nf)
#pragma unroll
            for (int r = 0; r < 4; ++r) acc[nf][r] *= scr[r];
    }

    for (int sb = 0; sb <= qblk; ++sb) {
        __syncthreads();
        {
            const int tt = tid >> 2, e0 = (tid & 3) * 24;
            const size_t rowb = (size_t)(b * S_ + s0 + sb * 64 + tt) * HID_ + hd * DH_ + e0;
#pragma unroll
            for (int jj = 0; jj < 3; ++jj) {
                *(u16x8*)&Ks[tt * 104 + e0 + jj * 8] = *(const u16x8*)(kb + rowb + jj * 8);
                const u16x8 vv = *(const u16x8*)(vb + rowb + jj * 8);
#pragma unroll
                for (int u = 0; u < 8; ++u)
                    vTs[(e0 + jj * 8 + u) * 72 + tt] = u2b(vv[u]);
            }
        }
        __syncthreads();
        f32x4 pacc[4];
#pragma unroll
        for (int nf = 0; nf < 4; ++nf) pacc[nf] = f32x4{0.f, 0.f, 0.f, 0.f};
#pragma unroll
        for (int ks = 0; ks < 3; ++ks) {
            const s16x8 af = *(const s16x8*)((const char*)Qs + (wid * 16 + l15) * 208 + ks * 64 + l4 * 16);
#pragma unroll
            for (int nf = 0; nf < 4; ++nf) {
                const s16x8 bf = *(const s16x8*)((const char*)Ks + (nf * 16 + l15) * 208 + ks * 64 + l4 * 16);
                pacc[nf] = __builtin_amdgcn_mfma_f32_16x16x32_bf16(af, bf, pacc[nf], 0, 0, 0);
            }
        }
#pragma unroll
        for (int nf = 0; nf < 4; ++nf) {
#pragma unroll
            for (int r = 0; r < 4; ++r) {
                const int tr = wid * 16 + l4 * 4 + r;
                const int sg = nf * 16 + l15;
                float p = 0.f;
                if (sb < qblk || sg <= tr)
                    p = pacc[nf][r] * __expf(fminf(wAL[sb * 64 + sg] + gL[tr], 0.f));
                Phs[tr * 72 + sg] = __float2bfloat16(p);
            }
        }
        __syncthreads();
#pragma unroll
        for (int ks = 0; ks < 2; ++ks) {
            const s16x8 af = *(const s16x8*)((const char*)Phs + (wid * 16 + l15) * 144 + ks * 64 + l4 * 16);
#pragma unroll
            for (int nf = 0; nf < 7; ++nf) {
                const s16x8 bf = *(const s16x8*)((const char*)vTs + (nf * 16 + l15) * 144 + ks * 64 + l4 * 16);
                acc[nf] = __builtin_amdgcn_mfma_f32_16x16x32_bf16(af, bf, acc[nf], 0, 0, 0);
            }
        }
    }

#pragma unroll
    for (int r = 0; r < 4; ++r) {
        float den = __shfl(acc[6][r], lane & 48);
        den = fmaxf(den, 1.0f);
        const int tr = wid * 16 + l4 * 4 + r;
        const size_t rowb = (size_t)(tq0 + tr) * HID_ + hd * DH_;
#pragma unroll
        for (int nf = 0; nf < 6; ++nf) {
            const int dc = nf * 16 + l15;
            const float o = __bfloat162float(ob[rowb + dc]);
            hb[rowb + dc] = o * acc[nf][r] / den;
        }
    }
}

// ---------------- (LN(h)+skip)*silu(r) -> compact bf16 pre [T,768] ----------------
__global__ __launch_bounds__(256) void epi1_kernel(const float* __restrict__ h,
                                                   const bf16_t* __restrict__ xskip,
                                                   const bf16_t* __restrict__ r,
                                                   const float* __restrict__ hw,
                                                   const float* __restrict__ hbi,
                                                   bf16_t* __restrict__ pre) {
    const int t = blockIdx.x, tid = threadIdx.x;
    const size_t rb = (size_t)t * HID_;
    float v0 = h[rb + tid], v1 = h[rb + tid + 256], v2 = h[rb + tid + 512];
    float sm = v0 + v1 + v2;
    float sq = v0 * v0 + v1 * v1 + v2 * v2;
#pragma unroll
    for (int off = 32; off > 0; off >>= 1) { sm += __shfl_xor(sm, off); sq += __shfl_xor(sq, off); }
    __shared__ float ws4[8];
    const int wid = tid >> 6, lane = tid & 63;
    if (lane == 0) { ws4[wid] = sm; ws4[4 + wid] = sq; }
    __syncthreads();
    sm = ws4[0] + ws4[1] + ws4[2] + ws4[3];
    sq = ws4[4] + ws4[5] + ws4[6] + ws4[7];
    const float mu = sm * (1.f / HID_);
    const float rs = rsqrtf(sq * (1.f / HID_) - mu * mu + 1e-6f);
    bf16_t* row = pre + (size_t)t * HID_;
#pragma unroll
    for (int k2 = 0; k2 < 3; ++k2) {
        const int c = tid + k2 * 256;
        const float v = (k2 == 0 ? v0 : k2 == 1 ? v1 : v2);
        float o = (v - mu) * rs * hw[c] + hbi[c] + __bfloat162float(xskip[rb + c]);
        const float rv = __bfloat162float(r[rb + c]);
        o *= rv * (1.f / (1.f + __expf(-rv)));
        row[c] = __float2bfloat16(o);
    }
}

extern "C" void kernel_launch(void* const* d_in, const int* in_sizes, int n_in,
                              void* d_out, int out_size, void* d_ws, size_t ws_size,
                              hipStream_t stream) {
    const float* x      = (const float*)d_in[0];
    const float* ln_w   = (const float*)d_in[1];
    const float* ln_b   = (const float*)d_in[2];
    const float* up_l_w = (const float*)d_in[3];
    const float* up_r_w = (const float*)d_in[4];
    const float* conv_w = (const float*)d_in[5];
    const float* skip_w = (const float*)d_in[6];
    const float* fused_w= (const float*)d_in[7];
    const float* fused_b= (const float*)d_in[8];
    const float* hid_w  = (const float*)d_in[9];
    const float* hid_b  = (const float*)d_in[10];
    const float* down_w = (const float*)d_in[11];
    float* out = (float*)d_out;
    (void)n_in; (void)out_size; (void)ws_size;

    const size_t T = (size_t)in_sizes[0] / D_;   // 16384
    const int B = (int)(T / S_);                 // 8

    // ---- workspace layout (< proven-safe 231.9 MB) ----
    char* ws = (char*)d_ws;
    size_t off = 0;
    auto take = [&](size_t bytes) -> char* {
        char* p = ws + off; off = (off + bytes + 255) & ~(size_t)255; return p;
    };
    // recurrence arena; the up/cat weights alias inside (dead before recurrence)
    char* arena = take(20123904);
    bf16_t* win_h = (bf16_t*)(arena);                       // [2304,768]  3,538,944 B
    bf16_t* win_l = (bf16_t*)(arena + 3538944);             // 3,538,944 B
    bf16_t* wcat  = (bf16_t*)(arena + 7077888);             // [3840,1536] 11,796,480 B (ends 18.9MB)
    float* Bst    = (float*)(arena);                        // 19,070,976 B
    float* wAarr  = (float*)(arena + 19071232);
    float* garr   = (float*)(arena + 19595520);
    float* mprevA = (float*)(arena + 20119808);
    float* alphaA = (float*)(arena + 20121856);

    bf16_t* wdn_h = (bf16_t*)take((size_t)D_ * HID_ * 2);   // survives until final GEMM
    char*   xnreg = take(T * 1536 * 2);   // xn compact bf16 -> xc-hi plane -> h fp32
    char*   big   = take(T * 1536 * 4);   // xl fp32 -> [o|q|k|v] bf16 -> pre bf16
    bf16_t* rbuf  = (bf16_t*)take(T * HID_ * 2);
    bf16_t* skipb = (bf16_t*)take(T * HID_ * 2);
    float*  gates = (float*)take(T * 16 * 4);

    bf16_t* xn   = (bf16_t*)xnreg;        // [T,768] bf16
    bf16_t* xch  = (bf16_t*)xnreg;        // [T,1536] bf16 (after xn dies)
    float*  h    = (float*)xnreg;         // [T,768] fp32 (after xch dies)
    float*  xl   = (float*)big;
    bf16_t* obuf = (bf16_t*)big;
    bf16_t* qbuf = (bf16_t*)(big + T * HID_ * 2);
    bf16_t* kbuf = (bf16_t*)(big + T * HID_ * 4);
    bf16_t* vbuf = (bf16_t*)(big + T * HID_ * 6);
    bf16_t* pre  = (bf16_t*)big;          // compact [T,768] (over o,q; dead)

    const int MT = (int)(T / 256);   // 64

    // 1. all weight conversions in one launch
    cvt_all_kernel<<<2048, 256, 0, stream>>>(up_l_w, up_r_w, skip_w, fused_w, down_w,
                                             win_h, win_l, wcat, wdn_h);
    // 2. LayerNorm -> compact xn
    ln_x_kernel<<<(int)T, 256, 0, stream>>>(x, ln_w, ln_b, xn);
    // 3. merged [xl | r] = xn @ [up_l|up_r]^T (2-pass on up_l cols, 1-pass on up_r)  N=2304, K=768
    gemm256<2, 4, 12><<<dim3(2304 / 256, MT), 512, 0, stream>>>(
        (const char*)xn, 1536, 0, win_h, win_l,
        rbuf, xl, 0, nullptr, nullptr, nullptr, nullptr, nullptr, nullptr);
    // 4. conv+silu -> compact xc-hi plane (xn dead); exact fp32 gates fused in
    conv_gate_kernel<<<(int)T, 192, 0, stream>>>(xl, conv_w, fused_w, fused_b, xch, gates);
    // 5. merged [skip | o,q,k,v] = xc_hi @ wcat^T (1-pass, N=3840)  K=1536
    gemm256<1, 2, 24><<<dim3(3840 / 256, MT), 512, 0, stream>>>(
        (const char*)xch, 3072, 0, wcat, nullptr,
        skipb, nullptr, 0, obuf, qbuf, kbuf, vbuf, fused_b + 16, nullptr);
    // 6. chunkwise-parallel recurrence -> h fp32 (arena weights dead now)
    mscan_kernel<<<B, 64, 0, stream>>>(gates, wAarr, garr, mprevA, alphaA);
    chunkA_kernel<<<dim3(NCH, B * NH_), 512, 0, stream>>>(kbuf, vbuf, wAarr, garr, Bst);
    chunkB_kernel<<<dim3(97, B * NH_), 96, 0, stream>>>(Bst, alphaA);
    chunkC_kernel<<<dim3(NCH * 4, B * NH_), 256, 0, stream>>>(qbuf, kbuf, vbuf, obuf,
                                                              wAarr, garr, mprevA, Bst, h);
    // 7. (LN(h)+skip)*silu(r) -> compact pre
    epi1_kernel<<<(int)T, 256, 0, stream>>>(h, skipb, rbuf, hid_w, hid_b, pre);
    // 8. out = pre @ down^T + x (1-pass)  K=768
    gemm256<1, 3, 12><<<dim3(HID_ / 256, MT), 512, 0, stream>>>(
        (const char*)pre, 1536, 0, wdn_h, nullptr,
        nullptr, out, HID_, nullptr, nullptr, nullptr, nullptr, nullptr, x);
}

// Round 12
// 687.763 us; speedup vs baseline: 1.0846x; 1.0846x over previous
//
#include <hip/hip_runtime.h>
#include <hip/hip_bf16.h>

#define D_    768
#define P_    1536
#define HID_  768
#define NH_   8
#define DH_   96
#define S_    2048
#define LCH   256     // recurrence chunk length
#define NCH   8       // chunks per sequence

typedef __hip_bfloat16 bf16_t;
typedef __attribute__((ext_vector_type(8))) short s16x8;
typedef __attribute__((ext_vector_type(8))) unsigned short u16x8;
typedef __attribute__((ext_vector_type(4))) float f32x4;

__device__ __forceinline__ float b2f(unsigned short u) {
    union { unsigned int i; float f; } x; x.i = ((unsigned int)u) << 16; return x.f;
}
__device__ __forceinline__ unsigned short f2b(float f) {
    bf16_t h = __float2bfloat16(f);
    unsigned short u; __builtin_memcpy(&u, &h, 2); return u;
}
__device__ __forceinline__ bf16_t u2b(unsigned short u) {
    bf16_t t; __builtin_memcpy(&t, &u, 2); return t;
}

// async global->LDS, 16B per lane (LDS dest = wave-uniform base + lane*16, linear layout)
__device__ __forceinline__ void gload16(const void* g, const void* l) {
    __builtin_amdgcn_global_load_lds(
        (const __attribute__((address_space(1))) unsigned int*)(unsigned long long)(g),
        (__attribute__((address_space(3))) unsigned int*)(unsigned int)(unsigned long long)(l),
        16, 0, 0);
}

// ---------------- all weight conversions in one grid-stride kernel ----------------
__global__ void cvt_all_kernel(const float* __restrict__ up_l_w, const float* __restrict__ up_r_w,
                               const float* __restrict__ skip_w, const float* __restrict__ fused_w,
                               const float* __restrict__ down_w,
                               bf16_t* __restrict__ win_h, bf16_t* __restrict__ win_l,
                               bf16_t* __restrict__ wcat, bf16_t* __restrict__ wdn) {
    const int N1 = 2304 * 768, N2 = 3840 * 1536, N3 = 768 * 768;
    int i = blockIdx.x * blockDim.x + threadIdx.x;
    const int stride = gridDim.x * blockDim.x;
    for (; i < N1 + N2 + N3; i += stride) {
        if (i < N1) {
            const float x = (i < 1536 * 768) ? up_l_w[i] : up_r_w[i - 1536 * 768];
            const bf16_t h = __float2bfloat16(x);
            win_h[i] = h;
            win_l[i] = __float2bfloat16(x - __bfloat162float(h));
        } else if (i < N1 + N2) {
            const int j = i - N1;
            const float x = (j < 768 * 1536) ? skip_w[j] : fused_w[16 * 1536 + (j - 768 * 1536)];
            wcat[j] = __float2bfloat16(x);
        } else {
            wdn[i - N1 - N2] = __float2bfloat16(down_w[i - N1 - N2]);
        }
    }
}

// ---------------- LayerNorm(x) -> compact bf16 [T,768] ----------------
__global__ __launch_bounds__(256) void ln_x_kernel(const float* __restrict__ x,
                                                   const float* __restrict__ w,
                                                   const float* __restrict__ b,
                                                   bf16_t* __restrict__ xn) {
    const int t = blockIdx.x, tid = threadIdx.x;
    const size_t rb = (size_t)t * D_;
    float v0 = x[rb + tid], v1 = x[rb + tid + 256], v2 = x[rb + tid + 512];
    float sm = v0 + v1 + v2;
    float sq = v0 * v0 + v1 * v1 + v2 * v2;
#pragma unroll
    for (int off = 32; off > 0; off >>= 1) { sm += __shfl_xor(sm, off); sq += __shfl_xor(sq, off); }
    __shared__ float ws4[8];
    const int wid = tid >> 6, lane = tid & 63;
    if (lane == 0) { ws4[wid] = sm; ws4[4 + wid] = sq; }
    __syncthreads();
    sm = ws4[0] + ws4[1] + ws4[2] + ws4[3];
    sq = ws4[4] + ws4[5] + ws4[6] + ws4[7];
    const float mu = sm * (1.f / D_);
    const float rs = rsqrtf(sq * (1.f / D_) - mu * mu + 1e-6f);
    bf16_t* row = xn + rb;
#pragma unroll
    for (int k2 = 0; k2 < 3; ++k2) {
        const int c = tid + k2 * 256;
        const float v = (k2 == 0 ? v0 : k2 == 1 ? v1 : v2);
        row[c] = __float2bfloat16((v - mu) * rs * w[c] + b[c]);
    }
}

// ---------------- conv(K=4)+SiLU from fp32 xl; writes compact xc-hi plane; fp32 gates fused ----------------
__global__ __launch_bounds__(192) void conv_gate_kernel(const float* __restrict__ xl,
                                                        const float* __restrict__ cw,
                                                        const float* __restrict__ fw,
                                                        const float* __restrict__ fb,
                                                        bf16_t* __restrict__ xch,
                                                        float* __restrict__ gates) {
    const int t = blockIdx.x, c = threadIdx.x;   // c: 8-float chunk, 192*8 = 1536
    const float* row = xl + (size_t)t * P_;
    const float4* r4 = (const float4*)row;
    float4 a = r4[2 * c], b4 = r4[2 * c + 1];
    float pm3 = 0.f, pm2 = 0.f, pm1 = 0.f;
    if (c > 0) { pm3 = row[c * 8 - 3]; pm2 = row[c * 8 - 2]; pm1 = row[c * 8 - 1]; }
    const float w0 = cw[0], w1 = cw[1], w2 = cw[2], w3 = cw[3];
    float xv[11] = {pm3, pm2, pm1, a.x, a.y, a.z, a.w, b4.x, b4.y, b4.z, b4.w};
    float xc[8];
    u16x8 h8;
#pragma unroll
    for (int j = 0; j < 8; ++j) {
        float s = w0 * xv[j] + w1 * xv[j + 1] + w2 * xv[j + 2] + w3 * xv[j + 3];
        s = s * (1.f / (1.f + __expf(-s)));   // SiLU
        xc[j] = s;
        h8[j] = f2b(s);
    }
    *(u16x8*)(xch + (size_t)t * P_ + c * 8) = h8;

    // fused exact-fp32 gate dots
    float pj[16];
#pragma unroll
    for (int j = 0; j < 16; ++j) {
        const float* wr = fw + (size_t)j * P_ + c * 8;
        float p = 0.f;
#pragma unroll
        for (int u = 0; u < 8; ++u) p += xc[u] * wr[u];
        pj[j] = p;
    }
#pragma unroll
    for (int j = 0; j < 16; ++j)
#pragma unroll
        for (int off = 32; off > 0; off >>= 1) pj[j] += __shfl_xor(pj[j], off);
    __shared__ float red[3][16];
    const int wv = c >> 6, ln = c & 63;
    if (ln == 0) {
#pragma unroll
        for (int j = 0; j < 16; ++j) red[wv][j] = pj[j];
    }
    __syncthreads();
    if (c < 16) {
        const float z = red[0][c] + red[1][c] + red[2][c] + fb[c];
        gates[(size_t)t * 16 + c] = 15.f * tanhf(z * (1.f / 15.f));
    }
}

// ============== 256x256 8-phase pipelined bf16 MFMA GEMM, C = A[M,K] * W[N,K]^T ==============
// Schedule identical to round 10 (verified PASS). NEW: co-scheduled 2D block mapping.
// Each XCD runs an 8-mt x 4-nt cohort of 32 blocks at a time:
//   xcd = orig&7; slot = orig>>3; batch = slot/32 (last batch partial);
//   nt = 4*batch + (slot%32)/8 ; mt = xcd*8 + slot%8        (requires gy == 64)
// Within a cohort every A K-tile is reused 4x and every W K-tile 8x at reuse distance
// ~2MB < 4MB L2 -> both streams become L2-resident; fabric/L3 traffic drops ~5x.
template <int NPASS, int MODE, int KTP>
__global__ __launch_bounds__(512, 2) void gemm256(
    const char* __restrict__ Ab, int astride, int aloff,
    const bf16_t* __restrict__ Wh, const bf16_t* __restrict__ Wl,
    bf16_t* __restrict__ out0, float* __restrict__ outf, int ldout,
    bf16_t* __restrict__ p1, bf16_t* __restrict__ p2,
    bf16_t* __restrict__ p3, bf16_t* __restrict__ p4,
    const float* __restrict__ bias, const float* __restrict__ resid) {
    __shared__ char smem[131072];
    const int tid = threadIdx.x;
    const int gx = gridDim.x;
    const int orig = blockIdx.y * gx + blockIdx.x;
    const int xcd = orig & 7;
    const int slot = orig >> 3;               // [0, gx*8) since gy == 64
    const int full = gx >> 2;                 // # of full 4-nt batches
    int bb, rr2;
    if (slot < (full << 5)) { bb = slot >> 5; rr2 = slot & 31; }
    else                    { bb = full;      rr2 = slot - (full << 5); }
    const int nt = (bb << 2) + (rr2 >> 3);
    const int mt = (xcd << 3) + (rr2 & 7);
    const int wid = tid >> 6, lane = tid & 63;
    const int wm = wid >> 2, wn = wid & 3;
    const int l15 = lane & 15, l4 = lane >> 4;
    const int sw = l15 & 7;
    const int co0 = ((l4 ^ sw) << 4);
    const int co1 = (((4 | l4) ^ sw) << 4);
    const int brb = (wn & 1) * 64;
    constexpr int VT = NPASS * KTP;
    const int vtm = (MODE == 4 && nt >= 6) ? KTP : VT;   // MODE 4 r-cols: Wh pass only
    const size_t wstride = (size_t)KTP * 128;   // W row bytes

    auto stage = [&](int h) {
        const int t = h >> 2;
        if (t >= vtm) return;
        const int m = h & 3;
        const int pass = t / KTP;
        const int k0b = (t - pass * KTP) << 7;
        char* ldsdst = smem + (size_t)(h & 7) * 16384;
        const char* src;
        size_t stride;
        if (m < 2) {
            src = Ab + (pass == 2 ? aloff : 0) + (size_t)(mt * 256 + m * 128) * astride + k0b;
            stride = (size_t)astride;
        } else {
            const bf16_t* wp = (pass == 1) ? Wl : Wh;
            src = (const char*)wp + (size_t)(nt * 256 + (m - 2) * 128) * wstride + k0b;
            stride = wstride;
        }
        const int r0 = tid >> 3, cd = tid & 7;
#pragma unroll
        for (int l = 0; l < 2; ++l) {
            const int row = l * 64 + r0;
            gload16(src + (size_t)row * stride + (size_t)((cd ^ (row & 7)) << 4),
                    ldsdst + l * 8192 + tid * 16);
        }
    };

    s16x8 a03[4], a03b[4], a47[4], a47b[4], b01[2], b01b[2], b23[2], b23b[2];
    auto readA03 = [&](const char* ldsA) {
#pragma unroll
        for (int i = 0; i < 4; ++i) {
            const char* rp = ldsA + (i * 16 + l15) * 128;
            a03[i] = *(const s16x8*)(rp + co0);
            a03b[i] = *(const s16x8*)(rp + co1);
        }
    };
    auto readA47 = [&](const char* ldsA) {
#pragma unroll
        for (int i = 0; i < 4; ++i) {
            const char* rp = ldsA + ((4 + i) * 16 + l15) * 128;
            a47[i] = *(const s16x8*)(rp + co0);
            a47b[i] = *(const s16x8*)(rp + co1);
        }
    };
    auto readB01 = [&](const char* ldsB) {
#pragma unroll
        for (int j = 0; j < 2; ++j) {
            const char* rp = ldsB + (brb + j * 16 + l15) * 128;
            b01[j] = *(const s16x8*)(rp + co0);
            b01b[j] = *(const s16x8*)(rp + co1);
        }
    };
    auto readB23 = [&](const char* ldsB) {
#pragma unroll
        for (int j = 0; j < 2; ++j) {
            const char* rp = ldsB + (brb + 32 + j * 16 + l15) * 128;
            b23[j] = *(const s16x8*)(rp + co0);
            b23b[j] = *(const s16x8*)(rp + co1);
        }
    };

    f32x4 acc[8][4];
#pragma unroll
    for (int i = 0; i < 8; ++i)
#pragma unroll
        for (int j = 0; j < 4; ++j) acc[i][j] = f32x4{0.f, 0.f, 0.f, 0.f};

    // prologue: tile0 all 4 halves + tile1 A-halves; pre-read tile0's ph0 operands
#pragma unroll
    for (int h = 0; h < 6; ++h) stage(h);
    asm volatile("s_waitcnt vmcnt(4)" ::: "memory");
    __builtin_amdgcn_s_barrier();
    readA03(smem + wm * 16384);
    readB01(smem + 32768 + (wn >> 1) * 16384);

    for (int vt = 0; vt < vtm; ++vt) {
        const char* ldsA = smem + (vt & 1) * 65536 + wm * 16384;
        const char* ldsB = smem + (vt & 1) * 65536 + 32768 + (wn >> 1) * 16384;
        const char* ldsAn = smem + ((vt + 1) & 1) * 65536 + wm * 16384;
        const char* ldsBn = smem + ((vt + 1) & 1) * 65536 + 32768 + (wn >> 1) * 16384;
        const int hb = vt * 4 + 6;

        // ---- phase 0: MFMA a03 x b01; prefetch b23; stage next tile's BOTH B halves
        stage(hb + 0);
        stage(hb + 1);
        __builtin_amdgcn_s_barrier();
        readB23(ldsB);
        __builtin_amdgcn_s_setprio(1);
#pragma unroll
        for (int i = 0; i < 4; ++i)
#pragma unroll
            for (int j = 0; j < 2; ++j) {
                acc[i][j] = __builtin_amdgcn_mfma_f32_16x16x32_bf16(a03[i], b01[j], acc[i][j], 0, 0, 0);
                acc[i][j] = __builtin_amdgcn_mfma_f32_16x16x32_bf16(a03b[i], b01b[j], acc[i][j], 0, 0, 0);
            }
        __builtin_amdgcn_s_setprio(0);
        asm volatile("s_waitcnt lgkmcnt(0)" ::: "memory");
        __builtin_amdgcn_s_barrier();

        // ---- phase 1: MFMA a03 x b23; prefetch a47 (no stage)
        __builtin_amdgcn_s_barrier();
        readA47(ldsA);
        __builtin_amdgcn_s_setprio(1);
#pragma unroll
        for (int i = 0; i < 4; ++i)
#pragma unroll
            for (int j = 0; j < 2; ++j) {
                acc[i][2 + j] = __builtin_amdgcn_mfma_f32_16x16x32_bf16(a03[i], b23[j], acc[i][2 + j], 0, 0, 0);
                acc[i][2 + j] = __builtin_amdgcn_mfma_f32_16x16x32_bf16(a03b[i], b23b[j], acc[i][2 + j], 0, 0, 0);
            }
        __builtin_amdgcn_s_setprio(0);
        asm volatile("s_waitcnt lgkmcnt(0)" ::: "memory");
        __builtin_amdgcn_s_barrier();

        // ---- phase 2: MFMA a47 x b01; stage tile(t+2) A0; drain next tile's 4 halves
        stage(hb + 2);
        __builtin_amdgcn_s_barrier();
        __builtin_amdgcn_s_setprio(1);
#pragma unroll
        for (int i = 0; i < 4; ++i)
#pragma unroll
            for (int j = 0; j < 2; ++j) {
                acc[4 + i][j] = __builtin_amdgcn_mfma_f32_16x16x32_bf16(a47[i], b01[j], acc[4 + i][j], 0, 0, 0);
                acc[4 + i][j] = __builtin_amdgcn_mfma_f32_16x16x32_bf16(a47b[i], b01b[j], acc[4 + i][j], 0, 0, 0);
            }
        __builtin_amdgcn_s_setprio(0);
        if (vt + 2 >= vtm) {   // TAIL: newest stages skipped -> must drain everything
            asm volatile("s_waitcnt vmcnt(0)" ::: "memory");
        } else {
            asm volatile("s_waitcnt vmcnt(2)" ::: "memory");
        }
        __builtin_amdgcn_s_barrier();

        // ---- phase 3: MFMA a47 x b23; stage tile(t+2) A1; prefetch next tile's a03,b01
        stage(hb + 3);
        __builtin_amdgcn_s_barrier();
        if (vt + 1 < vtm) { readA03(ldsAn); readB01(ldsBn); }
        __builtin_amdgcn_s_setprio(1);
#pragma unroll
        for (int i = 0; i < 4; ++i)
#pragma unroll
            for (int j = 0; j < 2; ++j) {
                acc[4 + i][2 + j] = __builtin_amdgcn_mfma_f32_16x16x32_bf16(a47[i], b23[j], acc[4 + i][2 + j], 0, 0, 0);
                acc[4 + i][2 + j] = __builtin_amdgcn_mfma_f32_16x16x32_bf16(a47b[i], b23b[j], acc[4 + i][2 + j], 0, 0, 0);
            }
        __builtin_amdgcn_s_setprio(0);
        asm volatile("s_waitcnt lgkmcnt(0)" ::: "memory");
        __builtin_amdgcn_s_barrier();
    }

    // ---- epilogue ----
    const int grow0 = mt * 256 + wm * 128;
    const int gcol0 = nt * 256 + wn * 64;
#pragma unroll
    for (int i = 0; i < 8; ++i) {
#pragma unroll
        for (int j = 0; j < 4; ++j) {
            const int gcol = gcol0 + j * 16 + l15;
#pragma unroll
            for (int r = 0; r < 4; ++r) {
                const int grow = grow0 + i * 16 + l4 * 4 + r;
                float v = acc[i][j][r];
                if constexpr (MODE == 0) {
                    out0[(size_t)grow * ldout + gcol] = __float2bfloat16(v);
                } else if constexpr (MODE == 1) {
                    outf[(size_t)grow * ldout + gcol] = v;
                } else if constexpr (MODE == 2) {
                    const int seg = gcol / 768;          // uniform per block (768 % 256 == 0)
                    const int col = gcol - seg * 768;
                    const size_t oo = (size_t)grow * 768 + col;
                    if (seg == 0) {
                        out0[oo] = __float2bfloat16(v);  // skip (no bias)
                    } else {
                        v += bias[gcol - 768];
                        if (seg == 1)      p1[oo] = __float2bfloat16(1.f / (1.f + __expf(-v)));
                        else if (seg == 2) p2[oo] = __float2bfloat16(v);
                        else if (seg == 3) p3[oo] = __float2bfloat16(v * 0.10206207261596577f); // 1/sqrt(96)
                        else               p4[oo] = __float2bfloat16(v);
                    }
                } else if constexpr (MODE == 3) {
                    const size_t oo = (size_t)grow * ldout + gcol;
                    outf[oo] = v + resid[oo];
                } else {   // MODE 4: merged up (xl fp32 | r bf16)
                    if (gcol < 1536) outf[(size_t)grow * 1536 + gcol] = v;
                    else             out0[(size_t)grow * 768 + (gcol - 1536)] = __float2bfloat16(v);
                }
            }
        }
    }
}

// ================= chunkwise-parallel mLSTM recurrence =================
// ---- 1. gate scan ----
__global__ __launch_bounds__(64) void mscan_kernel(const float* __restrict__ gates,
                                                   float* __restrict__ wAo, float* __restrict__ go,
                                                   float* __restrict__ mprev, float* __restrict__ alpha) {
    const int b = blockIdx.x;
    const int lane = threadIdx.x;
    const int hd = lane >> 3, c = lane & 7;
    const size_t gbase = ((size_t)b * S_ + c * LCH) * 16;
    float F = 0.f, I = -1e30f;
    for (int t = 0; t < LCH; ++t) {
        const float fi = gates[gbase + t * 16 + hd];
        const float ff = gates[gbase + t * 16 + 8 + hd];
        I = fmaxf(I + ff, fi);
        F += ff;
    }
    float Fs = F, Is = I;
#pragma unroll
    for (int off = 1; off < 8; off <<= 1) {
        const float Fo = __shfl_up(Fs, off);
        const float Io = __shfl_up(Is, off);
        if (c >= off) { Is = fmaxf(Io + Fs, Is); Fs = Fo + Fs; }
    }
    const float Fe = __shfl_up(Fs, 1);
    const float Ie = __shfl_up(Is, 1);
    const float mp = (c == 0) ? 0.f : fmaxf(Fe, Ie);
    float m = mp; F = 0.f;
    const size_t wbase = ((size_t)(b * NH_ + hd)) * S_ + c * LCH;
    for (int t = 0; t < LCH; ++t) {
        const float fi = gates[gbase + t * 16 + hd];
        const float ff = gates[gbase + t * 16 + 8 + hd];
        F += ff;
        m = fmaxf(ff + m, fi);
        wAo[wbase + t] = fi - F;
        go[wbase + t] = F - m;
    }
    const int idx = (b * NH_ + hd) * NCH + c;
    mprev[idx] = mp;
    alpha[idx] = __expf(fminf(mp + F - m, 0.f));
}

// ---- 2. chunk summaries: B_c = sum coeff_s v_s k_s^T; nB rides as vT row 96 = coeff ----
__global__ __launch_bounds__(512) void chunkA_kernel(
    const bf16_t* __restrict__ kb, const bf16_t* __restrict__ vb,
    const float* __restrict__ wAo, const float* __restrict__ go,
    float* __restrict__ Bst) {
    const int c = blockIdx.x, bh = blockIdx.y;
    const int b = bh >> 3, hd = bh & 7;
    __shared__ bf16_t kT[96 * 136];
    __shared__ bf16_t vTh[112 * 136];    // rows 0..95 = coeff*v^T, row 96 = coeff, 97..111 = 0
    __shared__ float coeffL[128];
    const int tid = threadIdx.x, lane = tid & 63, wid = tid >> 6;
    const int l15 = lane & 15, l4 = lane >> 4;
    const int s0 = c * LCH;
    const size_t seqb = (size_t)bh * S_;
    const float gend = go[seqb + s0 + LCH - 1];
    f32x4 acc[6];
#pragma unroll
    for (int nf = 0; nf < 6; ++nf) acc[nf] = f32x4{0.f, 0.f, 0.f, 0.f};

    {
        const bf16_t z16 = __float2bfloat16(0.f);
        for (int i = tid; i < 15 * 136; i += 512) vTh[97 * 136 + i] = z16;
    }

    for (int sb = 0; sb < 2; ++sb) {
        __syncthreads();
        if (tid < 128) {
            const float cf = __expf(fminf(wAo[seqb + s0 + sb * 128 + tid] + gend, 0.f));
            coeffL[tid] = cf;
            vTh[96 * 136 + tid] = __float2bfloat16(cf);
        }
        __syncthreads();
        {
            const int st = tid >> 2, e0 = (tid & 3) * 24;
            const size_t rowb = (size_t)(b * S_ + s0 + sb * 128 + st) * HID_ + hd * DH_ + e0;
            const float cf = coeffL[st];
#pragma unroll
            for (int jj = 0; jj < 3; ++jj) {
                const u16x8 kv = *(const u16x8*)(kb + rowb + jj * 8);
                const u16x8 vv = *(const u16x8*)(vb + rowb + jj * 8);
#pragma unroll
                for (int u = 0; u < 8; ++u) {
                    const int e = e0 + jj * 8 + u;
                    kT[e * 136 + st] = u2b(kv[u]);
                    vTh[e * 136 + st] = __float2bfloat16(b2f(vv[u]) * cf);
                }
            }
        }
        __syncthreads();
        if (wid < 7) {
#pragma unroll
            for (int ks = 0; ks < 4; ++ks) {
                const s16x8 af = *(const s16x8*)((const char*)vTh + (wid * 16 + l15) * 272 + ks * 64 + l4 * 16);
#pragma unroll
                for (int nf = 0; nf < 6; ++nf) {
                    const s16x8 bf = *(const s16x8*)((const char*)kT + (nf * 16 + l15) * 272 + ks * 64 + l4 * 16);
                    acc[nf] = __builtin_amdgcn_mfma_f32_16x16x32_bf16(af, bf, acc[nf], 0, 0, 0);
                }
            }
        }
    }
    float* outp = Bst + ((size_t)bh * NCH + c) * 9312;
    if (wid < 6) {
#pragma unroll
        for (int nf = 0; nf < 6; ++nf)
#pragma unroll
            for (int r = 0; r < 4; ++r)
                outp[(size_t)(wid * 16 + l4 * 4 + r) * 96 + nf * 16 + l15] = acc[nf][r];
    } else if (wid == 6 && l4 == 0) {
#pragma unroll
        for (int nf = 0; nf < 6; ++nf)
            outp[9216 + nf * 16 + l15] = acc[nf][0];
    }
}

// ---- 3. inter-chunk scan, in-place ----
__global__ __launch_bounds__(96) void chunkB_kernel(float* __restrict__ Bst,
                                                    const float* __restrict__ alpha) {
    const int idx = blockIdx.x * 96 + threadIdx.x;
    const int bh = blockIdx.y;
    float val = (idx < 9216) ? 0.f : 1.f;
    for (int c = 0; c < NCH; ++c) {
        float* p = Bst + ((size_t)bh * NCH + c) * 9312 + idx;
        const float t = *p;
        *p = val;
        val = alpha[bh * NCH + c] * val + t;
    }
}

// ---- 4. outputs: h = o * (inter + intra)/max(den,1), 64 q-rows per block ----
__global__ __launch_bounds__(256) void chunkC_kernel(
    const bf16_t* __restrict__ qb, const bf16_t* __restrict__ kb,
    const bf16_t* __restrict__ vb, const bf16_t* __restrict__ ob,
    const float* __restrict__ wAo, const float* __restrict__ go,
    const float* __restrict__ mprev, const float* __restrict__ Cst,
    float* __restrict__ hb) {
    const int c = blockIdx.x >> 2, qblk = blockIdx.x & 3;
    const int bh = blockIdx.y, b = bh >> 3, hd = bh & 7;
    __shared__ bf16_t Qs[64 * 104];
    __shared__ bf16_t Ks[64 * 104];
    __shared__ bf16_t vTs[112 * 72];
    __shared__ bf16_t Phs[64 * 72];
    __shared__ bf16_t CsH[112 * 104];
    __shared__ float wAL[256];
    __shared__ float gL[64];
    __shared__ float scL[64];
    const int tid = threadIdx.x, lane = tid & 63, wid = tid >> 6;
    const int l15 = lane & 15, l4 = lane >> 4;
    const int s0 = c * LCH;
    const size_t seqb = (size_t)bh * S_;
    const int tq0 = b * S_ + s0 + qblk * 64;

    wAL[tid] = wAo[seqb + s0 + tid];
    if (tid < 64) {
        const float gg = go[seqb + s0 + qblk * 64 + tid];
        gL[tid] = gg;
        scL[tid] = __expf(fminf(mprev[bh * NCH + c] + gg, 0.f));
    }
    {
        const int tt = tid >> 2, e0 = (tid & 3) * 24;
        const bf16_t* qrow = qb + (size_t)(tq0 + tt) * HID_ + hd * DH_ + e0;
#pragma unroll
        for (int jj = 0; jj < 3; ++jj)
            *(u16x8*)&Qs[tt * 104 + e0 + jj * 8] = *(const u16x8*)(qrow + jj * 8);
    }
    {
        const float* Csp = Cst + ((size_t)bh * NCH + c) * 9312;
        for (int i = tid; i < 9312; i += 256) {
            int dd, ee;
            if (i < 9216) { dd = i / 96; ee = i - dd * 96; }
            else          { dd = 96;     ee = i - 9216; }
            CsH[dd * 104 + ee] = __float2bfloat16(Csp[i]);
        }
        const bf16_t z16 = __float2bfloat16(0.f);
        for (int i = tid; i < 15 * 104; i += 256) CsH[97 * 104 + i] = z16;
        if (tid < 64) vTs[96 * 72 + tid] = __float2bfloat16(1.f);
        for (int i = tid; i < 15 * 72; i += 256) vTs[97 * 72 + i] = z16;
    }
    __syncthreads();

    f32x4 acc[7];
#pragma unroll
    for (int nf = 0; nf < 7; ++nf) acc[nf] = f32x4{0.f, 0.f, 0.f, 0.f};
#pragma unroll
    for (int ks = 0; ks < 3; ++ks) {
        const s16x8 af = *(const s16x8*)((const char*)Qs + (wid * 16 + l15) * 208 + ks * 64 + l4 * 16);
#pragma unroll
        for (int nf = 0; nf < 7; ++nf) {
            const s16x8 bf = *(const s16x8*)((const char*)CsH + (nf * 16 + l15) * 208 + ks * 64 + l4 * 16);
            acc[nf] = __builtin_amdgcn_mfma_f32_16x16x32_bf16(af, bf, acc[nf], 0, 0, 0);
        }
    }
    {
        float scr[4];
#pragma unroll
        for (int r = 0; r < 4; ++r) scr[r] = scL[wid * 16 + l4 * 4 + r];
#pragma unroll
        for (int nf = 0; nf < 7; ++nf)
#pragma unroll
            for (int r = 0; r < 4; ++r) acc[nf][r] *= scr[r];
    }

    for (int sb = 0; sb <= qblk; ++sb) {
        __syncthreads();
        {
            const int tt = tid >> 2, e0 = (tid & 3) * 24;
            const size_t rowb = (size_t)(b * S_ + s0 + sb * 64 + tt) * HID_ + hd * DH_ + e0;
#pragma unroll
            for (int jj = 0; jj < 3; ++jj) {
                *(u16x8*)&Ks[tt * 104 + e0 + jj * 8] = *(const u16x8*)(kb + rowb + jj * 8);
                const u16x8 vv = *(const u16x8*)(vb + rowb + jj * 8);
#pragma unroll
                for (int u = 0; u < 8; ++u)
                    vTs[(e0 + jj * 8 + u) * 72 + tt] = u2b(vv[u]);
            }
        }
        __syncthreads();
        f32x4 pacc[4];
#pragma unroll
        for (int nf = 0; nf < 4; ++nf) pacc[nf] = f32x4{0.f, 0.f, 0.f, 0.f};
#pragma unroll
        for (int ks = 0; ks < 3; ++ks) {
            const s16x8 af = *(const s16x8*)((const char*)Qs + (wid * 16 + l15) * 208 + ks * 64 + l4 * 16);
#pragma unroll
            for (int nf = 0; nf < 4; ++nf) {
                const s16x8 bf = *(const s16x8*)((const char*)Ks + (nf * 16 + l15) * 208 + ks * 64 + l4 * 16);
                pacc[nf] = __builtin_amdgcn_mfma_f32_16x16x32_bf16(af, bf, pacc[nf], 0, 0, 0);
            }
        }
#pragma unroll
        for (int nf = 0; nf < 4; ++nf) {
#pragma unroll
            for (int r = 0; r < 4; ++r) {
                const int tr = wid * 16 + l4 * 4 + r;
                const int sg = nf * 16 + l15;
                float p = 0.f;
                if (sb < qblk || sg <= tr)
                    p = pacc[nf][r] * __expf(fminf(wAL[sb * 64 + sg] + gL[tr], 0.f));
                Phs[tr * 72 + sg] = __float2bfloat16(p);
            }
        }
        __syncthreads();
#pragma unroll
        for (int ks = 0; ks < 2; ++ks) {
            const s16x8 af = *(const s16x8*)((const char*)Phs + (wid * 16 + l15) * 144 + ks * 64 + l4 * 16);
#pragma unroll
            for (int nf = 0; nf < 7; ++nf) {
                const s16x8 bf = *(const s16x8*)((const char*)vTs + (nf * 16 + l15) * 144 + ks * 64 + l4 * 16);
                acc[nf] = __builtin_amdgcn_mfma_f32_16x16x32_bf16(af, bf, acc[nf], 0, 0, 0);
            }
        }
    }

#pragma unroll
    for (int r = 0; r < 4; ++r) {
        float den = __shfl(acc[6][r], lane & 48);
        den = fmaxf(den, 1.0f);
        const int tr = wid * 16 + l4 * 4 + r;
        const size_t rowb = (size_t)(tq0 + tr) * HID_ + hd * DH_;
#pragma unroll
        for (int nf = 0; nf < 6; ++nf) {
            const int dc = nf * 16 + l15;
            const float o = __bfloat162float(ob[rowb + dc]);
            hb[rowb + dc] = o * acc[nf][r] / den;
        }
    }
}

// ---------------- (LN(h)+skip)*silu(r) -> compact bf16 pre [T,768] ----------------
__global__ __launch_bounds__(256) void epi1_kernel(const float* __restrict__ h,
                                                   const bf16_t* __restrict__ xskip,
                                                   const bf16_t* __restrict__ r,
                                                   const float* __restrict__ hw,
                                                   const float* __restrict__ hbi,
                                                   bf16_t* __restrict__ pre) {
    const int t = blockIdx.x, tid = threadIdx.x;
    const size_t rb = (size_t)t * HID_;
    float v0 = h[rb + tid], v1 = h[rb + tid + 256], v2 = h[rb + tid + 512];
    float sm = v0 + v1 + v2;
    float sq = v0 * v0 + v1 * v1 + v2 * v2;
#pragma unroll
    for (int off = 32; off > 0; off >>= 1) { sm += __shfl_xor(sm, off); sq += __shfl_xor(sq, off); }
    __shared__ float ws4[8];
    const int wid = tid >> 6, lane = tid & 63;
    if (lane == 0) { ws4[wid] = sm; ws4[4 + wid] = sq; }
    __syncthreads();
    sm = ws4[0] + ws4[1] + ws4[2] + ws4[3];
    sq = ws4[4] + ws4[5] + ws4[6] + ws4[7];
    const float mu = sm * (1.f / HID_);
    const float rs = rsqrtf(sq * (1.f / HID_) - mu * mu + 1e-6f);
    bf16_t* row = pre + (size_t)t * HID_;
#pragma unroll
    for (int k2 = 0; k2 < 3; ++k2) {
        const int c = tid + k2 * 256;
        const float v = (k2 == 0 ? v0 : k2 == 1 ? v1 : v2);
        float o = (v - mu) * rs * hw[c] + hbi[c] + __bfloat162float(xskip[rb + c]);
        const float rv = __bfloat162float(r[rb + c]);
        o *= rv * (1.f / (1.f + __expf(-rv)));
        row[c] = __float2bfloat16(o);
    }
}

extern "C" void kernel_launch(void* const* d_in, const int* in_sizes, int n_in,
                              void* d_out, int out_size, void* d_ws, size_t ws_size,
                              hipStream_t stream) {
    const float* x      = (const float*)d_in[0];
    const float* ln_w   = (const float*)d_in[1];
    const float* ln_b   = (const float*)d_in[2];
    const float* up_l_w = (const float*)d_in[3];
    const float* up_r_w = (const float*)d_in[4];
    const float* conv_w = (const float*)d_in[5];
    const float* skip_w = (const float*)d_in[6];
    const float* fused_w= (const float*)d_in[7];
    const float* fused_b= (const float*)d_in[8];
    const float* hid_w  = (const float*)d_in[9];
    const float* hid_b  = (const float*)d_in[10];
    const float* down_w = (const float*)d_in[11];
    float* out = (float*)d_out;
    (void)n_in; (void)out_size; (void)ws_size;

    const size_t T = (size_t)in_sizes[0] / D_;   // 16384
    const int B = (int)(T / S_);                 // 8

    // ---- workspace layout (< proven-safe 231.9 MB) ----
    char* ws = (char*)d_ws;
    size_t off = 0;
    auto take = [&](size_t bytes) -> char* {
        char* p = ws + off; off = (off + bytes + 255) & ~(size_t)255; return p;
    };
    // recurrence arena; the up/cat weights alias inside (dead before recurrence)
    char* arena = take(20123904);
    bf16_t* win_h = (bf16_t*)(arena);                       // [2304,768]  3,538,944 B
    bf16_t* win_l = (bf16_t*)(arena + 3538944);             // 3,538,944 B
    bf16_t* wcat  = (bf16_t*)(arena + 7077888);             // [3840,1536] 11,796,480 B (ends 18.9MB)
    float* Bst    = (float*)(arena);                        // 19,070,976 B
    float* wAarr  = (float*)(arena + 19071232);
    float* garr   = (float*)(arena + 19595520);
    float* mprevA = (float*)(arena + 20119808);
    float* alphaA = (float*)(arena + 20121856);

    bf16_t* wdn_h = (bf16_t*)take((size_t)D_ * HID_ * 2);   // survives until final GEMM
    char*   xnreg = take(T * 1536 * 2);   // xn compact bf16 -> xc-hi plane -> h fp32
    char*   big   = take(T * 1536 * 4);   // xl fp32 -> [o|q|k|v] bf16 -> pre bf16
    bf16_t* rbuf  = (bf16_t*)take(T * HID_ * 2);
    bf16_t* skipb = (bf16_t*)take(T * HID_ * 2);
    float*  gates = (float*)take(T * 16 * 4);

    bf16_t* xn   = (bf16_t*)xnreg;        // [T,768] bf16
    bf16_t* xch  = (bf16_t*)xnreg;        // [T,1536] bf16 (after xn dies)
    float*  h    = (float*)xnreg;         // [T,768] fp32 (after xch dies)
    float*  xl   = (float*)big;
    bf16_t* obuf = (bf16_t*)big;
    bf16_t* qbuf = (bf16_t*)(big + T * HID_ * 2);
    bf16_t* kbuf = (bf16_t*)(big + T * HID_ * 4);
    bf16_t* vbuf = (bf16_t*)(big + T * HID_ * 6);
    bf16_t* pre  = (bf16_t*)big;          // compact [T,768] (over o,q; dead)

    const int MT = (int)(T / 256);   // 64

    // 1. all weight conversions in one launch
    cvt_all_kernel<<<2048, 256, 0, stream>>>(up_l_w, up_r_w, skip_w, fused_w, down_w,
                                             win_h, win_l, wcat, wdn_h);
    // 2. LayerNorm -> compact xn
    ln_x_kernel<<<(int)T, 256, 0, stream>>>(x, ln_w, ln_b, xn);
    // 3. merged [xl | r] = xn @ [up_l|up_r]^T (2-pass on up_l cols, 1-pass on up_r)  N=2304, K=768
    gemm256<2, 4, 12><<<dim3(2304 / 256, MT), 512, 0, stream>>>(
        (const char*)xn, 1536, 0, win_h, win_l,
        rbuf, xl, 0, nullptr, nullptr, nullptr, nullptr, nullptr, nullptr);
    // 4. conv+silu -> compact xc-hi plane (xn dead); exact fp32 gates fused in
    conv_gate_kernel<<<(int)T, 192, 0, stream>>>(xl, conv_w, fused_w, fused_b, xch, gates);
    // 5. merged [skip | o,q,k,v] = xc_hi @ wcat^T (1-pass, N=3840)  K=1536
    gemm256<1, 2, 24><<<dim3(3840 / 256, MT), 512, 0, stream>>>(
        (const char*)xch, 3072, 0, wcat, nullptr,
        skipb, nullptr, 0, obuf, qbuf, kbuf, vbuf, fused_b + 16, nullptr);
    // 6. chunkwise-parallel recurrence -> h fp32 (arena weights dead now)
    mscan_kernel<<<B, 64, 0, stream>>>(gates, wAarr, garr, mprevA, alphaA);
    chunkA_kernel<<<dim3(NCH, B * NH_), 512, 0, stream>>>(kbuf, vbuf, wAarr, garr, Bst);
    chunkB_kernel<<<dim3(97, B * NH_), 96, 0, stream>>>(Bst, alphaA);
    chunkC_kernel<<<dim3(NCH * 4, B * NH_), 256, 0, stream>>>(qbuf, kbuf, vbuf, obuf,
                                                              wAarr, garr, mprevA, Bst, h);
    // 7. (LN(h)+skip)*silu(r) -> compact pre
    epi1_kernel<<<(int)T, 256, 0, stream>>>(h, skipb, rbuf, hid_w, hid_b, pre);
    // 8. out = pre @ down^T + x (1-pass)  K=768
    gemm256<1, 3, 12><<<dim3(HID_ / 256, MT), 512, 0, stream>>>(
        (const char*)pre, 1536, 0, wdn_h, nullptr,
        nullptr, out, HID_, nullptr, nullptr, nullptr, nullptr, nullptr, x);
}